// Round 8
// baseline (3228.333 us; speedup 1.0000x reference)
//
#include <hip/hip_runtime.h>

// DrosophilaOpticLobeCircuit: 100-step recurrent sparse circuit.
// R8: LDS-resident state. Batches are independent; one batch's r-plane is
// 49000 x bf16 = 98KB -> fits one CU's LDS (160KB on gfx950). 256 blocks =
// 8 batches x 32 target-chunks, 1 block/CU. Per step each block stages its
// batch's full r-plane into LDS (coalesced), then serves all random edge
// gathers from LDS (ds_read_u16) instead of the TA/L2 path that R5-R7
// proved to be the invariant binder (~10us/step regardless of request
// count / ILP / occupancy). CSR reads are per-target contiguous 16-lane
// runs (coalesced). v lives in [B][N] = d_out layout (k_out eliminated).
// Tm1-source edges folded once into cF (R7). Partial-LDS fallback if the
// runtime caps dynamic shared memory below N*2 bytes.

#define BLK 256
#define SBLK 1024          // step-kernel block (16 waves, 1 block/CU)
#define STEPS 100
#define NBATCH 8
static constexpr float DT_C = 0.1f;

__device__ __forceinline__ unsigned f2bf_rne(float x) {   // fp32 -> bf16 bits (RNE)
    unsigned u = __float_as_uint(x);
    return (u + 0x7FFFu + ((u >> 16) & 1u)) >> 16;
}

__global__ void k_zero(int* counts, int* countS, int* tm1_pos, int N) {
    int i = blockIdx.x * BLK + threadIdx.x;
    if (i < N) { counts[i] = 0; countS[i] = 0; tm1_pos[i] = -1; }
}

__global__ void k_tm1pos(const int* __restrict__ tm1_idx, int* tm1_pos, int NT) {
    int i = blockIdx.x * BLK + threadIdx.x;
    if (i < NT) tm1_pos[tm1_idx[i]] = i;
}

// per-target total + static (Tm1-source) counts + per-edge static flag
__global__ void k_hist(const int* __restrict__ srcI, const int* __restrict__ tgt,
                       const int* __restrict__ type_ids,
                       int* counts, int* countS, unsigned char* __restrict__ flagA,
                       int E) {
    int i = blockIdx.x * BLK + threadIdx.x;
    if (i >= E) return;
    int t = tgt[i];
    atomicAdd(&counts[t], 1);
    unsigned char st = (type_ids[srcI[i]] == 0) ? 1 : 0;
    if (st) atomicAdd(&countS[t], 1);
    flagA[i] = st;
}

__global__ void k_scan1(const int* __restrict__ counts, int* offsets, int* bsum, int N) {
    __shared__ int s[BLK];
    int tx = threadIdx.x;
    int i = blockIdx.x * BLK + tx;
    int v = (i < N) ? counts[i] : 0;
    s[tx] = v; __syncthreads();
    for (int d = 1; d < BLK; d <<= 1) {
        int t = (tx >= d) ? s[tx - d] : 0;
        __syncthreads();
        s[tx] += t;
        __syncthreads();
    }
    if (i < N) offsets[i] = s[tx] - v;
    if (tx == BLK - 1) bsum[blockIdx.x] = s[tx];
}

__global__ void k_scan2(int* bsum, int nb) {
    __shared__ int s[BLK];
    int tx = threadIdx.x;
    int v = (tx < nb) ? bsum[tx] : 0;
    s[tx] = v; __syncthreads();
    for (int d = 1; d < BLK; d <<= 1) {
        int t = (tx >= d) ? s[tx - d] : 0;
        __syncthreads();
        s[tx] += t;
        __syncthreads();
    }
    if (tx < nb) bsum[tx] = s[tx] - v;
}

__global__ void k_scan3(const int* __restrict__ bsum, int* offsets, int N, int E) {
    int i = blockIdx.x * BLK + threadIdx.x;
    if (i < N) {
        offsets[i] += bsum[i >> 8];
    } else if (i == N) {
        offsets[N] = E;
    }
}

__global__ void k_cursors(const int* __restrict__ offsets, const int* __restrict__ countS,
                          int* cursorD, int* cursorS, int* dynEnd, int N) {
    int i = blockIdx.x * BLK + threadIdx.x;
    if (i >= N) return;
    int o  = offsets[i];
    int dE = offsets[i + 1] - countS[i];
    cursorD[i] = o;
    cursorS[i] = dE;
    dynEnd[i]  = dE;
}

// CSR fill: entry = (bf16(w*scale) << 16) | src_u16 ; static edges -> suffix
__global__ void k_fill(const int* __restrict__ srcI, const int* __restrict__ tgtI,
                       const float* __restrict__ w,
                       const float* __restrict__ se, const float* __restrict__ si,
                       const unsigned char* __restrict__ flagA,
                       int* cursorD, int* cursorS, unsigned* __restrict__ csr, int E) {
    int i = blockIdx.x * BLK + threadIdx.x;
    if (i >= E) return;
    float wv = w[i];
    float sc = wv > 0.f ? se[0] : (wv < 0.f ? si[0] : 1.f);
    float sw = wv * sc;
    unsigned entry = (f2bf_rne(sw) << 16) | (unsigned)srcI[i];
    int t = tgtI[i];
    int pos = flagA[i] ? atomicAdd(&cursorS[t], 1) : atomicAdd(&cursorD[t], 1);
    csr[pos] = entry;
}

// init planes: v[b][n] (= d_out), r0/r1 planes [b][n] bf16. grid (gN, 8).
__global__ void k_initp(const float* __restrict__ tm1_in, const float* __restrict__ v_init,
                        const int* __restrict__ tm1_pos,
                        float* __restrict__ v, unsigned short* __restrict__ r0p,
                        unsigned short* __restrict__ r1p, int N, int NT) {
    int n = blockIdx.x * BLK + threadIdx.x;
    if (n >= N) return;
    int b = blockIdx.y;
    int k = tm1_pos[n];
    float val = (k >= 0) ? tm1_in[(size_t)b * NT + k] : v_init[(size_t)b * N + n];
    size_t ix = (size_t)b * N + n;
    v[ix] = val;
    unsigned short rr = (unsigned short)f2bf_rne(fmaxf(val, 0.f));
    r0p[ix] = rr;
    r1p[ix] = rr;
}

// rows (uint4 of 8 bf16 batches, for k_static's gathers) + coef2[n]
__global__ void k_rows(const unsigned short* __restrict__ r0p,
                       const int* __restrict__ tm1_pos, const int* __restrict__ type_ids,
                       const float* __restrict__ tau_p,
                       uint4* __restrict__ rows, float2* __restrict__ coef2, int N) {
    int n = blockIdx.x * BLK + threadIdx.x;
    if (n >= N) return;
    unsigned rr[8];
    #pragma unroll
    for (int b = 0; b < 8; ++b) rr[b] = r0p[(size_t)b * N + n];
    rows[n] = make_uint4(rr[0] | (rr[1] << 16), rr[2] | (rr[3] << 16),
                         rr[4] | (rr[5] << 16), rr[6] | (rr[7] << 16));
    float g = DT_C / tau_p[type_ids[n]];
    coef2[n] = make_float2((tm1_pos[n] >= 0) ? 0.f : (1.f - g), g);
}

// 8-lane-group butterfly transpose-reduce (lane sub gets batch-sub sum)
__device__ __forceinline__ float butterfly8(float4 a0, float4 a1, int sub) {
    int bit0 = sub & 1, bit1 = (sub >> 1) & 1, bit2 = (sub >> 2) & 1;
    float b0 = (bit0 ? a0.y : a0.x) + __shfl_xor(bit0 ? a0.x : a0.y, 1);
    float b1 = (bit0 ? a0.w : a0.z) + __shfl_xor(bit0 ? a0.z : a0.w, 1);
    float b2 = (bit0 ? a1.y : a1.x) + __shfl_xor(bit0 ? a1.x : a1.y, 1);
    float b3 = (bit0 ? a1.w : a1.z) + __shfl_xor(bit0 ? a1.z : a1.w, 1);
    float c0 = (bit1 ? b1 : b0) + __shfl_xor(bit1 ? b0 : b1, 2);
    float c1 = (bit1 ? b3 : b2) + __shfl_xor(bit1 ? b2 : b3, 2);
    return (bit2 ? c1 : c0) + __shfl_xor(bit2 ? c0 : c1, 4);
}

// one-shot static fold: cF[b][n] = (sum_static w*r_src[b] + bias[n]) * g
__global__ void k_static(const int* __restrict__ offsets, const int* __restrict__ dynEnd,
                         const unsigned* __restrict__ csr, const uint4* __restrict__ rows,
                         const float2* __restrict__ coef2, const float* __restrict__ bias,
                         float* __restrict__ cF, int N) {
    int tid = blockIdx.x * BLK + threadIdx.x;
    int n = tid >> 3;
    int sub = threadIdx.x & 7;
    if (n >= N) return;
    float g = coef2[n].y;
    int s = dynEnd[n], e = offsets[n + 1];
    float4 a0 = make_float4(0.f, 0.f, 0.f, 0.f);
    float4 a1 = make_float4(0.f, 0.f, 0.f, 0.f);
    for (int i = s + sub; i < e; i += 8) {
        unsigned ew = csr[i];
        float w = __uint_as_float(ew & 0xFFFF0000u);
        uint4 q = rows[ew & 0xFFFFu];
        a0.x = fmaf(w, __uint_as_float(q.x << 16),          a0.x);
        a0.y = fmaf(w, __uint_as_float(q.x & 0xFFFF0000u),  a0.y);
        a0.z = fmaf(w, __uint_as_float(q.y << 16),          a0.z);
        a0.w = fmaf(w, __uint_as_float(q.y & 0xFFFF0000u),  a0.w);
        a1.x = fmaf(w, __uint_as_float(q.z << 16),          a1.x);
        a1.y = fmaf(w, __uint_as_float(q.z & 0xFFFF0000u),  a1.y);
        a1.z = fmaf(w, __uint_as_float(q.w << 16),          a1.z);
        a1.w = fmaf(w, __uint_as_float(q.w & 0xFFFF0000u),  a1.w);
    }
    float syn = butterfly8(a0, a1, sub);
    cF[(size_t)sub * N + n] = (syn + bias[n]) * g;
}

// step: block = (batch b, chunk c). Stage r_prev plane [b][0..M) into LDS,
// then 16-lane groups process targets: coalesced CSR run + LDS gathers,
// 4-shuffle reduce, lane 0 updates v (=d_out) and writes r_next bf16.
__global__ __launch_bounds__(SBLK) void k_step_lds(
        const int* __restrict__ offsets, const int* __restrict__ dynEnd,
        const unsigned* __restrict__ csr,
        const float2* __restrict__ coef2, const float* __restrict__ cF,
        const unsigned short* __restrict__ r_prev,
        float* __restrict__ v, unsigned short* __restrict__ r_next,
        int N, int M, int CH) {
    extern __shared__ unsigned short lr[];
    int blk = blockIdx.x;
    int b = blk >> 5;                 // batch
    int c = blk & 31;                 // target chunk
    const unsigned short* rp = r_prev + (size_t)b * N;
    // stage first M entries of the batch's r-plane (uint4 = 8 bf16)
    const uint4* s4 = (const uint4*)rp;
    uint4* d4 = (uint4*)lr;
    int n4 = M >> 3;
    for (int i = threadIdx.x; i < n4; i += SBLK) d4[i] = s4[i];
    __syncthreads();

    int n0 = c * CH;
    int nEnd = n0 + CH; if (nEnd > N) nEnd = N;
    int g  = threadIdx.x >> 4;        // 16-lane group id within block (0..63)
    int sl = threadIdx.x & 15;
    for (int n = n0 + g; n < nEnd; n += SBLK / 16) {
        float2 cf = coef2[n];
        if (cf.x == 0.f) continue;    // Tm1 target: clamped, r constant
        int s = offsets[n], e = dynEnd[n];
        float acc = 0.f;
        for (int idx = s + sl; idx < e; idx += 16) {
            unsigned ew = csr[idx];
            int srcn = (int)(ew & 0xFFFFu);
            float w = __uint_as_float(ew & 0xFFFF0000u);
            float rv;
            if (srcn < M) rv = __uint_as_float((unsigned)lr[srcn] << 16);
            else          rv = __uint_as_float((unsigned)rp[srcn] << 16);
            acc = fmaf(w, rv, acc);
        }
        acc += __shfl_xor(acc, 1);
        acc += __shfl_xor(acc, 2);
        acc += __shfl_xor(acc, 4);
        acc += __shfl_xor(acc, 8);
        if (sl == 0) {
            size_t ix = (size_t)b * N + n;
            float vn = v[ix] * cf.x + acc * cf.y + cF[ix];
            v[ix] = vn;
            r_next[ix] = (unsigned short)f2bf_rne(fmaxf(vn, 0.f));
        }
    }
}

static inline size_t align16(size_t x) { return (x + 15) & ~(size_t)15; }

extern "C" void kernel_launch(void* const* d_in, const int* in_sizes, int n_in,
                              void* d_out, int out_size, void* d_ws, size_t ws_size,
                              hipStream_t stream) {
    const float* tm1_in  = (const float*)d_in[0];
    const float* v_init  = (const float*)d_in[1];
    const float* weights = (const float*)d_in[2];
    const float* bias    = (const float*)d_in[3];
    const float* tau_p   = (const float*)d_in[4];
    const float* se      = (const float*)d_in[5];
    const float* si      = (const float*)d_in[6];
    const int*   srcI    = (const int*)d_in[7];
    const int*   tgtI    = (const int*)d_in[8];
    const int*   type_ids= (const int*)d_in[9];
    const int*   tm1_idx = (const int*)d_in[10];

    const int E  = in_sizes[2];
    const int N  = in_sizes[3];
    const int NT = in_sizes[10];

    char* p = (char*)d_ws;
    size_t off = 0;
    auto take = [&](size_t bytes) { void* r = p + off; off += align16(bytes); return r; };
    int*      offsets = (int*)     take((size_t)(N + 1) * 4);
    int*      cursorD = (int*)     take((size_t)N * 4);
    int*      cursorS = (int*)     take((size_t)N * 4);
    int*      counts  = (int*)     take((size_t)N * 4);
    int*      countS  = (int*)     take((size_t)N * 4);
    int*      dynEnd  = (int*)     take((size_t)N * 4);
    int*      tm1_pos = (int*)     take((size_t)N * 4);
    int*      bsum    = (int*)     take(1024 * 4);
    unsigned char* flagA = (unsigned char*)take((size_t)E);
    unsigned* csr     = (unsigned*)take((size_t)E * 4);
    float2*   coef2   = (float2*)  take((size_t)N * 8);
    uint4*    rows    = (uint4*)   take((size_t)N * 16);
    float*    cF      = (float*)   take((size_t)N * 8 * 4);
    unsigned short* r0p = (unsigned short*)take((size_t)N * 8 * 2);  // [b][n]
    unsigned short* r1p = (unsigned short*)take((size_t)N * 8 * 2);
    (void)ws_size;

    float* v = (float*)d_out;       // v lives in d_out ([B][N] = output layout)

    const int gN  = (N + BLK - 1) / BLK;
    const int gN1 = (N + 1 + BLK - 1) / BLK;
    const int gE  = (E + BLK - 1) / BLK;
    const int gNT = (NT + BLK - 1) / BLK;
    const int g8  = (N * 8 + BLK - 1) / BLK;

    k_zero<<<gN, BLK, 0, stream>>>(counts, countS, tm1_pos, N);
    k_tm1pos<<<gNT, BLK, 0, stream>>>(tm1_idx, tm1_pos, NT);
    k_hist<<<gE, BLK, 0, stream>>>(srcI, tgtI, type_ids, counts, countS, flagA, E);
    k_scan1<<<gN, BLK, 0, stream>>>(counts, offsets, bsum, N);
    k_scan2<<<1, BLK, 0, stream>>>(bsum, gN);
    k_scan3<<<gN1, BLK, 0, stream>>>(bsum, offsets, N, E);
    k_cursors<<<gN, BLK, 0, stream>>>(offsets, countS, cursorD, cursorS, dynEnd, N);
    k_fill<<<gE, BLK, 0, stream>>>(srcI, tgtI, weights, se, si, flagA,
                                   cursorD, cursorS, csr, E);
    k_initp<<<dim3(gN, NBATCH), BLK, 0, stream>>>(tm1_in, v_init, tm1_pos,
                                                  v, r0p, r1p, N, NT);
    k_rows<<<gN, BLK, 0, stream>>>(r0p, tm1_pos, type_ids, tau_p, rows, coef2, N);
    k_static<<<g8, BLK, 0, stream>>>(offsets, dynEnd, csr, rows, coef2, bias, cF, N);

    // ---- LDS capacity (deterministic host queries; capture-safe) ----
    int dev = 0, maxShm = 0;
    hipGetDevice(&dev);
    hipDeviceGetAttribute(&maxShm, hipDeviceAttributeMaxSharedMemoryPerBlock, dev);
    size_t want = (size_t)N * 2;
    int cap = maxShm;
    if ((size_t)cap < want) {
        if (hipFuncSetAttribute((const void*)k_step_lds,
                                hipFuncAttributeMaxDynamicSharedMemorySize,
                                (int)want) == hipSuccess)
            cap = (int)want;
    }
    int M = N;
    if ((size_t)cap < want) M = (cap / 2) & ~7;   // entries, multiple of 8
    size_t shm = (size_t)M * 2;

    const int CH = (N + 31) / 32;                 // targets per chunk
    unsigned short* rb[2] = { r0p, r1p };
    for (int s = 0; s < STEPS; ++s) {
        k_step_lds<<<NBATCH * 32, SBLK, shm, stream>>>(
            offsets, dynEnd, csr, coef2, cF, rb[s & 1], v, rb[(s + 1) & 1],
            N, M, CH);
    }
    // v (= d_out) already holds the final state
}

// Round 9
// 1233.871 us; speedup vs baseline: 2.6164x; 2.6164x over previous
//
#include <hip/hip_runtime.h>

// DrosophilaOpticLobeCircuit: 100-step recurrent sparse circuit.
// R9 = R6's proven 8-lane step structure + R7's Tm1-source static fold +
// NON-TEMPORAL hints on every streaming access in the step loop (csr 5.5MB,
// v_w, cF). Mechanism under test: the csr stream thrashes the 4MB per-XCD
// L2 each step, evicting the 784KB r-plane so random gathers fall to LLC.
// nt loads mark the stream evict-first, keeping r L2-resident. r gathers
// and r_next stores stay normally cached.

#define BLK 256
#define STEPS 100
#define NBATCH 8
#define PRE 5              // static slots/lane (8 lanes: covers dyn degree <= 40)
static constexpr float DT_C = 0.1f;

typedef unsigned uv4 __attribute__((ext_vector_type(4)));

__device__ __forceinline__ unsigned f2bf_rne(float x) {   // fp32 -> bf16 bits (RNE)
    unsigned u = __float_as_uint(x);
    return (u + 0x7FFFu + ((u >> 16) & 1u)) >> 16;
}
__device__ __forceinline__ unsigned pk_bf2(float a, float b) {
    return f2bf_rne(a) | (f2bf_rne(b) << 16);
}

__global__ void k_zero(int* counts, int* countS, int* tm1_pos, int N) {
    int i = blockIdx.x * BLK + threadIdx.x;
    if (i < N) { counts[i] = 0; countS[i] = 0; tm1_pos[i] = -1; }
}

__global__ void k_tm1pos(const int* __restrict__ tm1_idx, int* tm1_pos, int NT) {
    int i = blockIdx.x * BLK + threadIdx.x;
    if (i < NT) tm1_pos[tm1_idx[i]] = i;
}

// per-target total + static (Tm1-source) counts + per-edge static flag
__global__ void k_hist(const int* __restrict__ srcI, const int* __restrict__ tgt,
                       const int* __restrict__ type_ids,
                       int* counts, int* countS, unsigned char* __restrict__ flagA,
                       int E) {
    int i = blockIdx.x * BLK + threadIdx.x;
    if (i >= E) return;
    int t = tgt[i];
    atomicAdd(&counts[t], 1);
    unsigned char st = (type_ids[srcI[i]] == 0) ? 1 : 0;
    if (st) atomicAdd(&countS[t], 1);
    flagA[i] = st;
}

__global__ void k_scan1(const int* __restrict__ counts, int* offsets, int* bsum, int N) {
    __shared__ int s[BLK];
    int tx = threadIdx.x;
    int i = blockIdx.x * BLK + tx;
    int v = (i < N) ? counts[i] : 0;
    s[tx] = v; __syncthreads();
    for (int d = 1; d < BLK; d <<= 1) {
        int t = (tx >= d) ? s[tx - d] : 0;
        __syncthreads();
        s[tx] += t;
        __syncthreads();
    }
    if (i < N) offsets[i] = s[tx] - v;
    if (tx == BLK - 1) bsum[blockIdx.x] = s[tx];
}

__global__ void k_scan2(int* bsum, int nb) {
    __shared__ int s[BLK];
    int tx = threadIdx.x;
    int v = (tx < nb) ? bsum[tx] : 0;
    s[tx] = v; __syncthreads();
    for (int d = 1; d < BLK; d <<= 1) {
        int t = (tx >= d) ? s[tx - d] : 0;
        __syncthreads();
        s[tx] += t;
        __syncthreads();
    }
    if (tx < nb) bsum[tx] = s[tx] - v;
}

// finish scan + init cursors + dynEnd in one pass
__global__ void k_scan3c(const int* __restrict__ bsum, const int* __restrict__ countS,
                         int* offsets, int* cursorD, int* cursorS, int* dynEnd,
                         int N, int E) {
    int i = blockIdx.x * BLK + threadIdx.x;
    if (i > N) return;
    if (i == N) { offsets[N] = E; return; }
    int o = offsets[i] + bsum[i >> 8];
    offsets[i] = o;
    // offsets[i+1] not finalized yet; derive end from counts via next pass?
    // -> dynEnd needs offsets[i+1]; compute it directly: offsets[i+1] =
    //    (scan result of i+1). We can't read it here reliably. Instead use
    //    counts-based: end = o + count[i]; static suffix = countS[i].
    //    (counts still intact.)
}

// cursors from finalized offsets (separate tiny pass, needs offsets[i+1])
__global__ void k_cursors(const int* __restrict__ offsets, const int* __restrict__ countS,
                          int* cursorD, int* cursorS, int* dynEnd, int N) {
    int i = blockIdx.x * BLK + threadIdx.x;
    if (i >= N) return;
    int o  = offsets[i];
    int dE = offsets[i + 1] - countS[i];
    cursorD[i] = o;
    cursorS[i] = dE;
    dynEnd[i]  = dE;
}

// CSR fill: entry = (bf16(w*scale) << 16) | src_u16 ; static edges -> suffix
__global__ void k_fill(const int* __restrict__ srcI, const int* __restrict__ tgtI,
                       const float* __restrict__ w,
                       const float* __restrict__ se, const float* __restrict__ si,
                       const unsigned char* __restrict__ flagA,
                       int* cursorD, int* cursorS, unsigned* __restrict__ csr, int E) {
    int i = blockIdx.x * BLK + threadIdx.x;
    if (i >= E) return;
    float wv = w[i];
    float sc = wv > 0.f ? se[0] : (wv < 0.f ? si[0] : 1.f);
    float sw = wv * sc;
    unsigned entry = (f2bf_rne(sw) << 16) | (unsigned)srcI[i];
    int t = tgtI[i];
    int pos = flagA[i] ? atomicAdd(&cursorS[t], 1) : atomicAdd(&cursorD[t], 1);
    csr[pos] = entry;
}

// init v_w[n][8] fp32, r0=r1 bf16 rows (uint4), coef2 = (1-g or 0 for Tm1, g)
__global__ void k_initv(const float* __restrict__ tm1_in, const float* __restrict__ v_init,
                        const float* __restrict__ tau_p,
                        const int* __restrict__ type_ids, const int* __restrict__ tm1_pos,
                        float* __restrict__ v_w, uint4* __restrict__ r0, uint4* __restrict__ r1,
                        float2* __restrict__ coef2, int N, int NT) {
    int n = blockIdx.x * BLK + threadIdx.x;
    if (n >= N) return;
    int k = tm1_pos[n];
    float g = DT_C / tau_p[type_ids[n]];
    coef2[n] = make_float2((k >= 0) ? 0.f : (1.f - g), g);
    float vv[NBATCH], rr[NBATCH];
    for (int b = 0; b < NBATCH; ++b) {
        float val = (k >= 0) ? tm1_in[b * NT + k] : v_init[b * N + n];
        vv[b] = val;
        rr[b] = fmaxf(val, 0.f);
    }
    float4* vp = (float4*)(v_w + (size_t)n * 8);
    vp[0] = make_float4(vv[0], vv[1], vv[2], vv[3]);
    vp[1] = make_float4(vv[4], vv[5], vv[6], vv[7]);
    uint4 rq = make_uint4(pk_bf2(rr[0], rr[1]), pk_bf2(rr[2], rr[3]),
                          pk_bf2(rr[4], rr[5]), pk_bf2(rr[6], rr[7]));
    r0[n] = rq;
    r1[n] = rq;
}

// 8-lane-group butterfly transpose-reduce (lane sub gets batch-sub sum)
__device__ __forceinline__ float butterfly8(float4 a0, float4 a1, int sub) {
    int bit0 = sub & 1, bit1 = (sub >> 1) & 1, bit2 = (sub >> 2) & 1;
    float b0 = (bit0 ? a0.y : a0.x) + __shfl_xor(bit0 ? a0.x : a0.y, 1);
    float b1 = (bit0 ? a0.w : a0.z) + __shfl_xor(bit0 ? a0.z : a0.w, 1);
    float b2 = (bit0 ? a1.y : a1.x) + __shfl_xor(bit0 ? a1.x : a1.y, 1);
    float b3 = (bit0 ? a1.w : a1.z) + __shfl_xor(bit0 ? a1.z : a1.w, 1);
    float c0 = (bit1 ? b1 : b0) + __shfl_xor(bit1 ? b0 : b1, 2);
    float c1 = (bit1 ? b3 : b2) + __shfl_xor(bit1 ? b2 : b3, 2);
    return (bit2 ? c1 : c0) + __shfl_xor(bit2 ? c0 : c1, 4);
}

// one-shot static fold: cF[n*8+sub] = (sum_static w*r_src[sub] + bias[n]) * g
__global__ void k_static(const int* __restrict__ offsets, const int* __restrict__ dynEnd,
                         const unsigned* __restrict__ csr, const uint4* __restrict__ r0,
                         const float2* __restrict__ coef2, const float* __restrict__ bias,
                         float* __restrict__ cF, int N) {
    int tid = blockIdx.x * BLK + threadIdx.x;
    int n = tid >> 3;
    int sub = threadIdx.x & 7;
    if (n >= N) return;
    float g = coef2[n].y;
    int s = dynEnd[n], e = offsets[n + 1];
    float4 a0 = make_float4(0.f, 0.f, 0.f, 0.f);
    float4 a1 = make_float4(0.f, 0.f, 0.f, 0.f);
    for (int i = s + sub; i < e; i += 8) {
        unsigned ew = csr[i];
        float w = __uint_as_float(ew & 0xFFFF0000u);
        uint4 q = r0[ew & 0xFFFFu];
        a0.x = fmaf(w, __uint_as_float(q.x << 16),          a0.x);
        a0.y = fmaf(w, __uint_as_float(q.x & 0xFFFF0000u),  a0.y);
        a0.z = fmaf(w, __uint_as_float(q.y << 16),          a0.z);
        a0.w = fmaf(w, __uint_as_float(q.y & 0xFFFF0000u),  a0.w);
        a1.x = fmaf(w, __uint_as_float(q.z << 16),          a1.x);
        a1.y = fmaf(w, __uint_as_float(q.z & 0xFFFF0000u),  a1.y);
        a1.z = fmaf(w, __uint_as_float(q.w << 16),          a1.z);
        a1.w = fmaf(w, __uint_as_float(q.w & 0xFFFF0000u),  a1.w);
    }
    float syn = butterfly8(a0, a1, sub);
    cF[(size_t)n * 8 + sub] = (syn + bias[n]) * g;
}

// step: 8-lane group per target; phases A(csr nt loads)/B(row gathers cached)
// /C(FMA); streams (csr, v_w, cF) are non-temporal so the r-plane stays
// L2-resident; r gathers + r_next stores normally cached.
__global__ __launch_bounds__(BLK) void k_step(
        const int* __restrict__ offsets, const int* __restrict__ dynEnd,
        const unsigned* __restrict__ csr,
        const float2* __restrict__ coef2, const float* __restrict__ cF,
        const uv4* __restrict__ r_prev,
        float* __restrict__ v_w, unsigned short* __restrict__ r_next, int N) {
    int tid = blockIdx.x * BLK + threadIdx.x;
    int n = tid >> 3;
    int sub = threadIdx.x & 7;
    if (n >= N) return;
    float2 cf = coef2[n];
    if (cf.x == 0.f) return;                 // Tm1 target: clamped, r constant
    int s = offsets[n], e = dynEnd[n];

    // phase A: csr entries (independent nt loads)
    float wj[PRE];
    int   sj[PRE];
    #pragma unroll
    for (int j = 0; j < PRE; ++j) {
        int idx = s + sub + 8 * j;
        unsigned ew = (idx < e) ? __builtin_nontemporal_load(csr + idx) : 0u;
        wj[j] = __uint_as_float(ew & 0xFFFF0000u);
        sj[j] = (int)(ew & 0xFFFFu);
    }
    // phase B: row gathers (independent, cached)
    uv4 q[PRE];
    #pragma unroll
    for (int j = 0; j < PRE; ++j) {
        int idx = s + sub + 8 * j;
        q[j] = (idx < e) ? r_prev[sj[j]] : (uv4)(0u);
    }
    // phase C: unpack + accumulate
    float4 a0 = make_float4(0.f, 0.f, 0.f, 0.f);
    float4 a1 = make_float4(0.f, 0.f, 0.f, 0.f);
    #pragma unroll
    for (int j = 0; j < PRE; ++j) {
        float w = wj[j];
        a0.x = fmaf(w, __uint_as_float(q[j].x << 16),          a0.x);
        a0.y = fmaf(w, __uint_as_float(q[j].x & 0xFFFF0000u),  a0.y);
        a0.z = fmaf(w, __uint_as_float(q[j].y << 16),          a0.z);
        a0.w = fmaf(w, __uint_as_float(q[j].y & 0xFFFF0000u),  a0.w);
        a1.x = fmaf(w, __uint_as_float(q[j].z << 16),          a1.x);
        a1.y = fmaf(w, __uint_as_float(q[j].z & 0xFFFF0000u),  a1.y);
        a1.z = fmaf(w, __uint_as_float(q[j].w << 16),          a1.z);
        a1.w = fmaf(w, __uint_as_float(q[j].w & 0xFFFF0000u),  a1.w);
    }
    // tail: dynamic degree > 8*PRE
    for (int i = s + sub + 8 * PRE; i < e; i += 8) {
        unsigned ew = __builtin_nontemporal_load(csr + i);
        float w = __uint_as_float(ew & 0xFFFF0000u);
        uv4 qq = r_prev[ew & 0xFFFFu];
        a0.x = fmaf(w, __uint_as_float(qq.x << 16),          a0.x);
        a0.y = fmaf(w, __uint_as_float(qq.x & 0xFFFF0000u),  a0.y);
        a0.z = fmaf(w, __uint_as_float(qq.y << 16),          a0.z);
        a0.w = fmaf(w, __uint_as_float(qq.y & 0xFFFF0000u),  a0.w);
        a1.x = fmaf(w, __uint_as_float(qq.z << 16),          a1.x);
        a1.y = fmaf(w, __uint_as_float(qq.z & 0xFFFF0000u),  a1.y);
        a1.z = fmaf(w, __uint_as_float(qq.w << 16),          a1.z);
        a1.w = fmaf(w, __uint_as_float(qq.w & 0xFFFF0000u),  a1.w);
    }
    float syn = butterfly8(a0, a1, sub);
    size_t idx = (size_t)n * 8 + sub;
    float vo = __builtin_nontemporal_load(v_w + idx);
    float cf3 = __builtin_nontemporal_load(cF + idx);
    float vn = vo * cf.x + syn * cf.y + cf3;
    __builtin_nontemporal_store(vn, v_w + idx);
    r_next[idx] = (unsigned short)f2bf_rne(fmaxf(vn, 0.f));
}

__global__ void k_out(const float* __restrict__ v_w, float* __restrict__ out, int N) {
    int t = blockIdx.x * BLK + threadIdx.x;
    if (t >= NBATCH * N) return;
    int b = t / N;
    int n = t - b * N;
    out[t] = v_w[(size_t)n * 8 + b];
}

static inline size_t align16(size_t x) { return (x + 15) & ~(size_t)15; }

extern "C" void kernel_launch(void* const* d_in, const int* in_sizes, int n_in,
                              void* d_out, int out_size, void* d_ws, size_t ws_size,
                              hipStream_t stream) {
    const float* tm1_in  = (const float*)d_in[0];
    const float* v_init  = (const float*)d_in[1];
    const float* weights = (const float*)d_in[2];
    const float* bias    = (const float*)d_in[3];
    const float* tau_p   = (const float*)d_in[4];
    const float* se      = (const float*)d_in[5];
    const float* si      = (const float*)d_in[6];
    const int*   srcI    = (const int*)d_in[7];
    const int*   tgtI    = (const int*)d_in[8];
    const int*   type_ids= (const int*)d_in[9];
    const int*   tm1_idx = (const int*)d_in[10];

    const int E  = in_sizes[2];
    const int N  = in_sizes[3];
    const int NT = in_sizes[10];

    char* p = (char*)d_ws;
    size_t off = 0;
    auto take = [&](size_t bytes) { void* r = p + off; off += align16(bytes); return r; };
    int*      offsets = (int*)     take((size_t)(N + 1) * 4);
    int*      cursorD = (int*)     take((size_t)N * 4);
    int*      cursorS = (int*)     take((size_t)N * 4);
    int*      counts  = (int*)     take((size_t)N * 4);
    int*      countS  = (int*)     take((size_t)N * 4);
    int*      dynEnd  = (int*)     take((size_t)N * 4);
    int*      tm1_pos = (int*)     take((size_t)N * 4);
    int*      bsum    = (int*)     take(1024 * 4);
    unsigned char* flagA = (unsigned char*)take((size_t)E);
    unsigned* csr     = (unsigned*)take((size_t)E * 4);
    float2*   coef2   = (float2*)  take((size_t)N * 8);
    float*    cF      = (float*)   take((size_t)N * 8 * 4);
    float*    v_w     = (float*)   take((size_t)N * 8 * 4);
    uint4*    r0      = (uint4*)   take((size_t)N * 16);     // bf16 rows
    uint4*    r1      = (uint4*)   take((size_t)N * 16);
    (void)ws_size;

    const int gN  = (N + BLK - 1) / BLK;
    const int gN1 = (N + 1 + BLK - 1) / BLK;
    const int gE  = (E + BLK - 1) / BLK;
    const int gNT = (NT + BLK - 1) / BLK;
    const int g8  = (N * 8 + BLK - 1) / BLK;

    k_zero<<<gN, BLK, 0, stream>>>(counts, countS, tm1_pos, N);
    k_tm1pos<<<gNT, BLK, 0, stream>>>(tm1_idx, tm1_pos, NT);
    k_hist<<<gE, BLK, 0, stream>>>(srcI, tgtI, type_ids, counts, countS, flagA, E);
    k_scan1<<<gN, BLK, 0, stream>>>(counts, offsets, bsum, N);
    k_scan2<<<1, BLK, 0, stream>>>(bsum, gN);
    k_scan3c<<<gN1, BLK, 0, stream>>>(bsum, countS, offsets, cursorD, cursorS,
                                      dynEnd, N, E);
    k_cursors<<<gN, BLK, 0, stream>>>(offsets, countS, cursorD, cursorS, dynEnd, N);
    k_fill<<<gE, BLK, 0, stream>>>(srcI, tgtI, weights, se, si, flagA,
                                   cursorD, cursorS, csr, E);
    k_initv<<<gN, BLK, 0, stream>>>(tm1_in, v_init, tau_p, type_ids, tm1_pos,
                                    v_w, r0, r1, coef2, N, NT);
    k_static<<<g8, BLK, 0, stream>>>(offsets, dynEnd, csr, r0, coef2, bias, cF, N);

    uint4* rb[2] = { r0, r1 };
    for (int s = 0; s < STEPS; ++s) {
        k_step<<<g8, BLK, 0, stream>>>(offsets, dynEnd, csr, coef2, cF,
                                       (const uv4*)rb[s & 1], v_w,
                                       (unsigned short*)rb[(s + 1) & 1], N);
    }
    k_out<<<g8, BLK, 0, stream>>>(v_w, (float*)d_out, N);
}

// Round 10
// 1157.912 us; speedup vs baseline: 2.7881x; 1.0656x over previous
//
#include <hip/hip_runtime.h>

// DrosophilaOpticLobeCircuit: 100-step recurrent sparse circuit.
// R10 = R9 step structure (8-lane groups, compressed CSR u16src|bf16w, bf16 r
// rows, Tm1-source static fold, nt hints) with the setup chain rebuilt:
//  - k_fill's 1.6M random 4B scatters (100MB amplified writebacks across 8
//    non-coherent XCD L2s) replaced by a two-phase LDS counting sort:
//    k_bucket: per-4096-edge chunk LDS sort -> bucket-contiguous 128B runs
//    k_place:  one block per bucket, exact CSR placement within a ~25KB
//              single-owner region (L2 write-combining works).
//  - k_out fused into the last k_step (out param).
// Step loop itself is MSHR*latency-bound (~9.5us/step) per R5-R9 evidence.

#define BLK 256
#define STEPS 100
#define NBATCH 8
#define PRE 6              // static slots/lane (8 lanes: covers dyn degree <= 48)
#define NBUCK 256
#define CHUNK 4096
#define PERT 16            // CHUNK / 256 threads
static constexpr float DT_C = 0.1f;

typedef unsigned uv4 __attribute__((ext_vector_type(4)));

__device__ __forceinline__ unsigned f2bf_rne(float x) {   // fp32 -> bf16 bits (RNE)
    unsigned u = __float_as_uint(x);
    return (u + 0x7FFFu + ((u >> 16) & 1u)) >> 16;
}
__device__ __forceinline__ unsigned pk_bf2(float a, float b) {
    return f2bf_rne(a) | (f2bf_rne(b) << 16);
}

__global__ void k_zero(int* counts, int* countS, int* tm1_pos, int N) {
    int i = blockIdx.x * BLK + threadIdx.x;
    if (i < N) { counts[i] = 0; countS[i] = 0; tm1_pos[i] = -1; }
}

__global__ void k_tm1pos(const int* __restrict__ tm1_idx, int* tm1_pos, int NT) {
    int i = blockIdx.x * BLK + threadIdx.x;
    if (i < NT) tm1_pos[tm1_idx[i]] = i;
}

// per-target total + static (Tm1-source) counts + per-edge static flag
__global__ void k_hist(const int* __restrict__ srcI, const int* __restrict__ tgt,
                       const int* __restrict__ type_ids,
                       int* counts, int* countS, unsigned char* __restrict__ flagA,
                       int E) {
    int i = blockIdx.x * BLK + threadIdx.x;
    if (i >= E) return;
    int t = tgt[i];
    atomicAdd(&counts[t], 1);
    unsigned char st = (type_ids[srcI[i]] == 0) ? 1 : 0;
    if (st) atomicAdd(&countS[t], 1);
    flagA[i] = st;
}

__global__ void k_scan1(const int* __restrict__ counts, int* offsets, int* bsum, int N) {
    __shared__ int s[BLK];
    int tx = threadIdx.x;
    int i = blockIdx.x * BLK + tx;
    int v = (i < N) ? counts[i] : 0;
    s[tx] = v; __syncthreads();
    for (int d = 1; d < BLK; d <<= 1) {
        int t = (tx >= d) ? s[tx - d] : 0;
        __syncthreads();
        s[tx] += t;
        __syncthreads();
    }
    if (i < N) offsets[i] = s[tx] - v;
    if (tx == BLK - 1) bsum[blockIdx.x] = s[tx];
}

__global__ void k_scan2(int* bsum, int nb) {
    __shared__ int s[BLK];
    int tx = threadIdx.x;
    int v = (tx < nb) ? bsum[tx] : 0;
    s[tx] = v; __syncthreads();
    for (int d = 1; d < BLK; d <<= 1) {
        int t = (tx >= d) ? s[tx - d] : 0;
        __syncthreads();
        s[tx] += t;
        __syncthreads();
    }
    if (tx < nb) bsum[tx] = s[tx] - v;
}

__global__ void k_scan3(const int* __restrict__ bsum, int* offsets, int N, int E) {
    int i = blockIdx.x * BLK + threadIdx.x;
    if (i < N) offsets[i] += bsum[i >> 8];
    else if (i == N) offsets[N] = E;
}

// dynEnd per target + per-bucket global cursors (= offsets at bucket start)
__global__ void k_prep(const int* __restrict__ offsets, const int* __restrict__ countS,
                       int* dynEnd, int* gCursor, int N, int span) {
    int i = blockIdx.x * BLK + threadIdx.x;
    if (i < N) dynEnd[i] = offsets[i + 1] - countS[i];
    if (i < NBUCK) {
        int t0 = i * span; if (t0 > N) t0 = N;
        gCursor[i] = offsets[t0];
    }
}

// phase 1: LDS counting sort of 4096-edge chunks into bucket-contiguous runs.
// staged entry (u64): [15:0]=tgt, [31:16]=src, [47:32]=bf16(w*scale), [63]=static
__global__ __launch_bounds__(256) void k_bucket(
        const int* __restrict__ srcI, const int* __restrict__ tgtI,
        const float* __restrict__ w,
        const float* __restrict__ se, const float* __restrict__ si,
        const unsigned char* __restrict__ flagA,
        int* gCursor, unsigned long long* __restrict__ csr_tmp, int E, int span) {
    __shared__ unsigned long long stg[CHUNK];
    __shared__ int hcnt[NBUCK], hcur[NBUCK], hbase[NBUCK], gb[NBUCK], sc1[NBUCK];
    int base = blockIdx.x * CHUNK;
    int cnt = E - base; if (cnt > CHUNK) cnt = CHUNK;
    int tx = threadIdx.x;
    hcnt[tx] = 0;
    __syncthreads();

    float sE = se[0], sI = si[0];
    unsigned long long ent[PERT];
    int ebk[PERT];
    #pragma unroll
    for (int k = 0; k < PERT; ++k) {
        int o = k * 256 + tx;
        ent[k] = 0; ebk[k] = -1;
        if (o < cnt) {
            int i = base + o;
            int t = tgtI[i], s = srcI[i];
            float wv = w[i];
            float sc = wv > 0.f ? sE : (wv < 0.f ? sI : 1.f);
            unsigned wb = f2bf_rne(wv * sc);
            unsigned long long fl = flagA[i] ? (1ull << 63) : 0ull;
            ent[k] = (unsigned long long)(unsigned)t
                   | ((unsigned long long)(unsigned)s << 16)
                   | ((unsigned long long)wb << 32) | fl;
            int b = t / span;
            ebk[k] = b;
            atomicAdd(&hcnt[b], 1);
        }
    }
    __syncthreads();
    // exclusive scan of hcnt (256 == blockDim)
    int v = hcnt[tx];
    sc1[tx] = v; __syncthreads();
    for (int d = 1; d < NBUCK; d <<= 1) {
        int t2 = (tx >= d) ? sc1[tx - d] : 0;
        __syncthreads();
        sc1[tx] += t2;
        __syncthreads();
    }
    hbase[tx] = sc1[tx] - v;
    hcur[tx]  = sc1[tx] - v;
    gb[tx] = atomicAdd(&gCursor[tx], v);     // reserve global run for this chunk
    __syncthreads();
    // rank + stage (bucket-sorted within chunk)
    #pragma unroll
    for (int k = 0; k < PERT; ++k) {
        if (ebk[k] >= 0) {
            int r = atomicAdd(&hcur[ebk[k]], 1);
            stg[r] = ent[k];
        }
    }
    __syncthreads();
    // coalesced copy-out: consecutive idx mostly share a bucket -> line runs
    for (int idx = tx; idx < cnt; idx += 256) {
        unsigned long long e = stg[idx];
        int b = (int)(e & 0xFFFFu) / span;
        csr_tmp[gb[b] + (idx - hbase[b])] = e;
    }
}

// phase 2: one block per bucket; exact CSR placement with LDS per-target
// cursors (dyn prefix / static suffix). Region is single-owner -> L2 combines.
__global__ __launch_bounds__(256) void k_place(
        const int* __restrict__ offsets, const int* __restrict__ dynEnd,
        const unsigned long long* __restrict__ csr_tmp,
        unsigned* __restrict__ csr, int N, int span) {
    __shared__ int curD[256], curS[256];
    int b = blockIdx.x;
    int n0 = b * span;
    int nE = n0 + span; if (nE > N) nE = N;
    if (n0 >= N) return;
    int tx = threadIdx.x;
    for (int l = tx; l < nE - n0; l += 256) {
        curD[l] = offsets[n0 + l];
        curS[l] = dynEnd[n0 + l];
    }
    __syncthreads();
    int s = offsets[n0], e = offsets[nE];
    for (int i = s + tx; i < e; i += 256) {
        unsigned long long en = csr_tmp[i];
        int t = (int)(en & 0xFFFFu);
        int l = t - n0;
        int pos = (en >> 63) ? atomicAdd(&curS[l], 1) : atomicAdd(&curD[l], 1);
        unsigned src = (unsigned)((en >> 16) & 0xFFFFu);
        unsigned wb  = (unsigned)((en >> 32) & 0xFFFFu);
        csr[pos] = (wb << 16) | src;
    }
}

// init v_w[n][8] fp32, r0=r1 bf16 rows (uint4), coef2 = (1-g or 0 for Tm1, g)
__global__ void k_initv(const float* __restrict__ tm1_in, const float* __restrict__ v_init,
                        const float* __restrict__ tau_p,
                        const int* __restrict__ type_ids, const int* __restrict__ tm1_pos,
                        float* __restrict__ v_w, uint4* __restrict__ r0, uint4* __restrict__ r1,
                        float2* __restrict__ coef2, int N, int NT) {
    int n = blockIdx.x * BLK + threadIdx.x;
    if (n >= N) return;
    int k = tm1_pos[n];
    float g = DT_C / tau_p[type_ids[n]];
    coef2[n] = make_float2((k >= 0) ? 0.f : (1.f - g), g);
    float vv[NBATCH], rr[NBATCH];
    for (int b = 0; b < NBATCH; ++b) {
        float val = (k >= 0) ? tm1_in[b * NT + k] : v_init[b * N + n];
        vv[b] = val;
        rr[b] = fmaxf(val, 0.f);
    }
    float4* vp = (float4*)(v_w + (size_t)n * 8);
    vp[0] = make_float4(vv[0], vv[1], vv[2], vv[3]);
    vp[1] = make_float4(vv[4], vv[5], vv[6], vv[7]);
    uint4 rq = make_uint4(pk_bf2(rr[0], rr[1]), pk_bf2(rr[2], rr[3]),
                          pk_bf2(rr[4], rr[5]), pk_bf2(rr[6], rr[7]));
    r0[n] = rq;
    r1[n] = rq;
}

// 8-lane-group butterfly transpose-reduce (lane sub gets batch-sub sum)
__device__ __forceinline__ float butterfly8(float4 a0, float4 a1, int sub) {
    int bit0 = sub & 1, bit1 = (sub >> 1) & 1, bit2 = (sub >> 2) & 1;
    float b0 = (bit0 ? a0.y : a0.x) + __shfl_xor(bit0 ? a0.x : a0.y, 1);
    float b1 = (bit0 ? a0.w : a0.z) + __shfl_xor(bit0 ? a0.z : a0.w, 1);
    float b2 = (bit0 ? a1.y : a1.x) + __shfl_xor(bit0 ? a1.x : a1.y, 1);
    float b3 = (bit0 ? a1.w : a1.z) + __shfl_xor(bit0 ? a1.z : a1.w, 1);
    float c0 = (bit1 ? b1 : b0) + __shfl_xor(bit1 ? b0 : b1, 2);
    float c1 = (bit1 ? b3 : b2) + __shfl_xor(bit1 ? b2 : b3, 2);
    return (bit2 ? c1 : c0) + __shfl_xor(bit2 ? c0 : c1, 4);
}

// one-shot static fold: cF[n*8+sub] = (sum_static w*r_src[sub] + bias[n]) * g
__global__ void k_static(const int* __restrict__ offsets, const int* __restrict__ dynEnd,
                         const unsigned* __restrict__ csr, const uint4* __restrict__ r0,
                         const float2* __restrict__ coef2, const float* __restrict__ bias,
                         float* __restrict__ cF, int N) {
    int tid = blockIdx.x * BLK + threadIdx.x;
    int n = tid >> 3;
    int sub = threadIdx.x & 7;
    if (n >= N) return;
    float g = coef2[n].y;
    int s = dynEnd[n], e = offsets[n + 1];
    float4 a0 = make_float4(0.f, 0.f, 0.f, 0.f);
    float4 a1 = make_float4(0.f, 0.f, 0.f, 0.f);
    for (int i = s + sub; i < e; i += 8) {
        unsigned ew = csr[i];
        float w = __uint_as_float(ew & 0xFFFF0000u);
        uint4 q = r0[ew & 0xFFFFu];
        a0.x = fmaf(w, __uint_as_float(q.x << 16),          a0.x);
        a0.y = fmaf(w, __uint_as_float(q.x & 0xFFFF0000u),  a0.y);
        a0.z = fmaf(w, __uint_as_float(q.y << 16),          a0.z);
        a0.w = fmaf(w, __uint_as_float(q.y & 0xFFFF0000u),  a0.w);
        a1.x = fmaf(w, __uint_as_float(q.z << 16),          a1.x);
        a1.y = fmaf(w, __uint_as_float(q.z & 0xFFFF0000u),  a1.y);
        a1.z = fmaf(w, __uint_as_float(q.w << 16),          a1.z);
        a1.w = fmaf(w, __uint_as_float(q.w & 0xFFFF0000u),  a1.w);
    }
    float syn = butterfly8(a0, a1, sub);
    cF[(size_t)n * 8 + sub] = (syn + bias[n]) * g;
}

// step: 8-lane group per target; phases A(csr)/B(gather)/C(FMA).
// out != nullptr on the LAST step: write d_out[b][n] instead of v_w/r_next.
__global__ __launch_bounds__(BLK) void k_step(
        const int* __restrict__ offsets, const int* __restrict__ dynEnd,
        const unsigned* __restrict__ csr,
        const float2* __restrict__ coef2, const float* __restrict__ cF,
        const uv4* __restrict__ r_prev,
        float* __restrict__ v_w, unsigned short* __restrict__ r_next,
        float* __restrict__ out, int N) {
    int tid = blockIdx.x * BLK + threadIdx.x;
    int n = tid >> 3;
    int sub = threadIdx.x & 7;
    if (n >= N) return;
    float2 cf = coef2[n];
    size_t idx = (size_t)n * 8 + sub;
    if (cf.x == 0.f) {                        // Tm1 target: clamped
        if (out) out[(size_t)sub * N + n] = v_w[idx];
        return;
    }
    int s = offsets[n], e = dynEnd[n];

    float wj[PRE];
    int   sj[PRE];
    #pragma unroll
    for (int j = 0; j < PRE; ++j) {
        int i2 = s + sub + 8 * j;
        unsigned ew = (i2 < e) ? __builtin_nontemporal_load(csr + i2) : 0u;
        wj[j] = __uint_as_float(ew & 0xFFFF0000u);
        sj[j] = (int)(ew & 0xFFFFu);
    }
    uv4 q[PRE];
    #pragma unroll
    for (int j = 0; j < PRE; ++j) {
        int i2 = s + sub + 8 * j;
        q[j] = (i2 < e) ? r_prev[sj[j]] : (uv4)(0u);
    }
    float4 a0 = make_float4(0.f, 0.f, 0.f, 0.f);
    float4 a1 = make_float4(0.f, 0.f, 0.f, 0.f);
    #pragma unroll
    for (int j = 0; j < PRE; ++j) {
        float w = wj[j];
        a0.x = fmaf(w, __uint_as_float(q[j].x << 16),          a0.x);
        a0.y = fmaf(w, __uint_as_float(q[j].x & 0xFFFF0000u),  a0.y);
        a0.z = fmaf(w, __uint_as_float(q[j].y << 16),          a0.z);
        a0.w = fmaf(w, __uint_as_float(q[j].y & 0xFFFF0000u),  a0.w);
        a1.x = fmaf(w, __uint_as_float(q[j].z << 16),          a1.x);
        a1.y = fmaf(w, __uint_as_float(q[j].z & 0xFFFF0000u),  a1.y);
        a1.z = fmaf(w, __uint_as_float(q[j].w << 16),          a1.z);
        a1.w = fmaf(w, __uint_as_float(q[j].w & 0xFFFF0000u),  a1.w);
    }
    for (int i2 = s + sub + 8 * PRE; i2 < e; i2 += 8) {
        unsigned ew = __builtin_nontemporal_load(csr + i2);
        float w = __uint_as_float(ew & 0xFFFF0000u);
        uv4 qq = r_prev[ew & 0xFFFFu];
        a0.x = fmaf(w, __uint_as_float(qq.x << 16),          a0.x);
        a0.y = fmaf(w, __uint_as_float(qq.x & 0xFFFF0000u),  a0.y);
        a0.z = fmaf(w, __uint_as_float(qq.y << 16),          a0.z);
        a0.w = fmaf(w, __uint_as_float(qq.y & 0xFFFF0000u),  a0.w);
        a1.x = fmaf(w, __uint_as_float(qq.z << 16),          a1.x);
        a1.y = fmaf(w, __uint_as_float(qq.z & 0xFFFF0000u),  a1.y);
        a1.z = fmaf(w, __uint_as_float(qq.w << 16),          a1.z);
        a1.w = fmaf(w, __uint_as_float(qq.w & 0xFFFF0000u),  a1.w);
    }
    float syn = butterfly8(a0, a1, sub);
    float vo = __builtin_nontemporal_load(v_w + idx);
    float cf3 = __builtin_nontemporal_load(cF + idx);
    float vn = vo * cf.x + syn * cf.y + cf3;
    if (out) {
        out[(size_t)sub * N + n] = vn;
    } else {
        __builtin_nontemporal_store(vn, v_w + idx);
        r_next[idx] = (unsigned short)f2bf_rne(fmaxf(vn, 0.f));
    }
}

static inline size_t align16(size_t x) { return (x + 15) & ~(size_t)15; }

extern "C" void kernel_launch(void* const* d_in, const int* in_sizes, int n_in,
                              void* d_out, int out_size, void* d_ws, size_t ws_size,
                              hipStream_t stream) {
    const float* tm1_in  = (const float*)d_in[0];
    const float* v_init  = (const float*)d_in[1];
    const float* weights = (const float*)d_in[2];
    const float* bias    = (const float*)d_in[3];
    const float* tau_p   = (const float*)d_in[4];
    const float* se      = (const float*)d_in[5];
    const float* si      = (const float*)d_in[6];
    const int*   srcI    = (const int*)d_in[7];
    const int*   tgtI    = (const int*)d_in[8];
    const int*   type_ids= (const int*)d_in[9];
    const int*   tm1_idx = (const int*)d_in[10];

    const int E  = in_sizes[2];
    const int N  = in_sizes[3];
    const int NT = in_sizes[10];
    const int span = (N + NBUCK - 1) / NBUCK;   // targets per bucket (<=256 for this N)

    char* p = (char*)d_ws;
    size_t off = 0;
    auto take = [&](size_t bytes) { void* r = p + off; off += align16(bytes); return r; };
    int*      offsets = (int*)     take((size_t)(N + 1) * 4);
    int*      counts  = (int*)     take((size_t)N * 4);
    int*      countS  = (int*)     take((size_t)N * 4);
    int*      dynEnd  = (int*)     take((size_t)N * 4);
    int*      tm1_pos = (int*)     take((size_t)N * 4);
    int*      bsum    = (int*)     take(1024 * 4);
    int*      gCursor = (int*)     take(NBUCK * 4);
    unsigned char* flagA = (unsigned char*)take((size_t)E);
    unsigned* csr     = (unsigned*)take((size_t)E * 4);
    unsigned long long* csr_tmp = (unsigned long long*)take((size_t)E * 8);
    float2*   coef2   = (float2*)  take((size_t)N * 8);
    float*    cF      = (float*)   take((size_t)N * 8 * 4);
    float*    v_w     = (float*)   take((size_t)N * 8 * 4);
    uint4*    r0      = (uint4*)   take((size_t)N * 16);     // bf16 rows
    uint4*    r1      = (uint4*)   take((size_t)N * 16);
    (void)ws_size;

    const int gN  = (N + BLK - 1) / BLK;
    const int gN1 = (N + 1 + BLK - 1) / BLK;
    const int gE  = (E + BLK - 1) / BLK;
    const int gNT = (NT + BLK - 1) / BLK;
    const int g8  = (N * 8 + BLK - 1) / BLK;
    const int gCH = (E + CHUNK - 1) / CHUNK;

    k_zero<<<gN, BLK, 0, stream>>>(counts, countS, tm1_pos, N);
    k_tm1pos<<<gNT, BLK, 0, stream>>>(tm1_idx, tm1_pos, NT);
    k_hist<<<gE, BLK, 0, stream>>>(srcI, tgtI, type_ids, counts, countS, flagA, E);
    k_scan1<<<gN, BLK, 0, stream>>>(counts, offsets, bsum, N);
    k_scan2<<<1, BLK, 0, stream>>>(bsum, gN);
    k_scan3<<<gN1, BLK, 0, stream>>>(bsum, offsets, N, E);
    k_prep<<<gN, BLK, 0, stream>>>(offsets, countS, dynEnd, gCursor, N, span);
    k_bucket<<<gCH, 256, 0, stream>>>(srcI, tgtI, weights, se, si, flagA,
                                      gCursor, csr_tmp, E, span);
    k_place<<<NBUCK, 256, 0, stream>>>(offsets, dynEnd, csr_tmp, csr, N, span);
    k_initv<<<gN, BLK, 0, stream>>>(tm1_in, v_init, tau_p, type_ids, tm1_pos,
                                    v_w, r0, r1, coef2, N, NT);
    k_static<<<g8, BLK, 0, stream>>>(offsets, dynEnd, csr, r0, coef2, bias, cF, N);

    uint4* rb[2] = { r0, r1 };
    for (int s = 0; s < STEPS; ++s) {
        float* outp = (s == STEPS - 1) ? (float*)d_out : nullptr;
        k_step<<<g8, BLK, 0, stream>>>(offsets, dynEnd, csr, coef2, cF,
                                       (const uv4*)rb[s & 1], v_w,
                                       (unsigned short*)rb[(s + 1) & 1],
                                       outp, N);
    }
}

// Round 11
// 1073.098 us; speedup vs baseline: 3.0084x; 1.0790x over previous
//
#include <hip/hip_runtime.h>

// DrosophilaOpticLobeCircuit: 100-step recurrent sparse circuit.
// R11 = R10 step loop (8-lane groups, u16src|bf16w CSR, bf16 r rows, Tm1-
// source static fold, nt hints) with the setup chain made fully bucket-local:
//  - NO global per-target histogram/scan (R10's k_hist was 82us / 58MB of
//    random 4B atomic writebacks across 8 non-coherent XCD L2s).
//  - k_bcount: LDS 256-bucket hist per 4096-edge chunk -> 256 atomics/block.
//  - k_bscan:  one-block scan -> bucket bases/cursors.
//  - k_bucket: chunk LDS counting sort -> bucket-contiguous csr_tmp runs
//              (Tm1-source flag computed inline from type_ids[src]).
//  - k_place:  per bucket: LDS per-target dyn/static counts + scan ->
//              offsets/dynEnd (coalesced) + exact CSR placement in its
//              single-owner region.

#define BLK 256
#define STEPS 100
#define NBATCH 8
#define PRE 6              // static slots/lane (8 lanes: covers dyn degree <= 48)
#define NBUCK 256
#define CHUNK 4096
#define PERT 16            // CHUNK / 256 threads
static constexpr float DT_C = 0.1f;

typedef unsigned uv4 __attribute__((ext_vector_type(4)));

__device__ __forceinline__ unsigned f2bf_rne(float x) {   // fp32 -> bf16 bits (RNE)
    unsigned u = __float_as_uint(x);
    return (u + 0x7FFFu + ((u >> 16) & 1u)) >> 16;
}
__device__ __forceinline__ unsigned pk_bf2(float a, float b) {
    return f2bf_rne(a) | (f2bf_rne(b) << 16);
}

__global__ void k_zero(int* tm1_pos, int* bcount, int N) {
    int i = blockIdx.x * BLK + threadIdx.x;
    if (i < N) tm1_pos[i] = -1;
    if (i < NBUCK) bcount[i] = 0;
}

__global__ void k_tm1pos(const int* __restrict__ tm1_idx, int* tm1_pos, int NT) {
    int i = blockIdx.x * BLK + threadIdx.x;
    if (i < NT) tm1_pos[tm1_idx[i]] = i;
}

// per-bucket edge counts: LDS hist per chunk, 256 global atomics per block
__global__ __launch_bounds__(256) void k_bcount(const int* __restrict__ tgtI,
                                                int* bcount, int E, int span) {
    __shared__ int h[NBUCK];
    int tx = threadIdx.x;
    h[tx] = 0;
    __syncthreads();
    int base = blockIdx.x * CHUNK;
    int cnt = E - base; if (cnt > CHUNK) cnt = CHUNK;
    for (int o = tx; o < cnt; o += 256)
        atomicAdd(&h[tgtI[base + o] / span], 1);
    __syncthreads();
    if (h[tx]) atomicAdd(&bcount[tx], h[tx]);
}

// one-block scan of bucket counts -> bbase[257], gCursor
__global__ void k_bscan(const int* __restrict__ bcount, int* bbase, int* gCursor) {
    __shared__ int s[NBUCK];
    int tx = threadIdx.x;
    int v = bcount[tx];
    s[tx] = v; __syncthreads();
    for (int d = 1; d < NBUCK; d <<= 1) {
        int t = (tx >= d) ? s[tx - d] : 0;
        __syncthreads();
        s[tx] += t;
        __syncthreads();
    }
    bbase[tx]   = s[tx] - v;
    gCursor[tx] = s[tx] - v;
    if (tx == NBUCK - 1) bbase[NBUCK] = s[tx];
}

// phase 1: LDS counting sort of 4096-edge chunks into bucket-contiguous runs.
// staged entry (u64): [15:0]=tgt, [31:16]=src, [47:32]=bf16(w*scale), [63]=static
__global__ __launch_bounds__(256) void k_bucket(
        const int* __restrict__ srcI, const int* __restrict__ tgtI,
        const float* __restrict__ w, const int* __restrict__ type_ids,
        const float* __restrict__ se, const float* __restrict__ si,
        int* gCursor, unsigned long long* __restrict__ csr_tmp, int E, int span) {
    __shared__ unsigned long long stg[CHUNK];
    __shared__ int hcnt[NBUCK], hcur[NBUCK], hbase[NBUCK], gb[NBUCK], sc1[NBUCK];
    int base = blockIdx.x * CHUNK;
    int cnt = E - base; if (cnt > CHUNK) cnt = CHUNK;
    int tx = threadIdx.x;
    hcnt[tx] = 0;
    __syncthreads();

    float sE = se[0], sI = si[0];
    unsigned long long ent[PERT];
    int ebk[PERT];
    #pragma unroll
    for (int k = 0; k < PERT; ++k) {
        int o = k * 256 + tx;
        ent[k] = 0; ebk[k] = -1;
        if (o < cnt) {
            int i = base + o;
            int t = tgtI[i], s = srcI[i];
            float wv = w[i];
            float sc = wv > 0.f ? sE : (wv < 0.f ? sI : 1.f);
            unsigned wb = f2bf_rne(wv * sc);
            unsigned long long fl = (type_ids[s] == 0) ? (1ull << 63) : 0ull;
            ent[k] = (unsigned long long)(unsigned)t
                   | ((unsigned long long)(unsigned)s << 16)
                   | ((unsigned long long)wb << 32) | fl;
            int b = t / span;
            ebk[k] = b;
            atomicAdd(&hcnt[b], 1);
        }
    }
    __syncthreads();
    int v = hcnt[tx];
    sc1[tx] = v; __syncthreads();
    for (int d = 1; d < NBUCK; d <<= 1) {
        int t2 = (tx >= d) ? sc1[tx - d] : 0;
        __syncthreads();
        sc1[tx] += t2;
        __syncthreads();
    }
    hbase[tx] = sc1[tx] - v;
    hcur[tx]  = sc1[tx] - v;
    gb[tx] = atomicAdd(&gCursor[tx], v);     // reserve global run for this chunk
    __syncthreads();
    #pragma unroll
    for (int k = 0; k < PERT; ++k) {
        if (ebk[k] >= 0) {
            int r = atomicAdd(&hcur[ebk[k]], 1);
            stg[r] = ent[k];
        }
    }
    __syncthreads();
    for (int idx = tx; idx < cnt; idx += 256) {
        unsigned long long e = stg[idx];
        int b = (int)(e & 0xFFFFu) / span;
        csr_tmp[gb[b] + (idx - hbase[b])] = e;
    }
}

// phase 2: one block per bucket. LDS per-target dyn/static counts + scan ->
// offsets/dynEnd (coalesced writes), then exact placement into the bucket's
// single-owner CSR region.
__global__ __launch_bounds__(256) void k_place(
        const unsigned long long* __restrict__ csr_tmp,
        const int* __restrict__ bbase,
        unsigned* __restrict__ csr, int* __restrict__ offsets,
        int* __restrict__ dynEnd, int N, int E, int span) {
    __shared__ int cntD[256], cntS[256], tb[256], curD[256], curS[256];
    int b = blockIdx.x;
    int n0 = b * span;
    int nT = N - n0; if (nT > span) nT = span;
    int tx = threadIdx.x;
    cntD[tx] = 0; cntS[tx] = 0;
    __syncthreads();
    int rs = bbase[b], re = bbase[b + 1];
    for (int i = rs + tx; i < re; i += 256) {
        unsigned long long en = csr_tmp[i];
        int l = (int)(en & 0xFFFFu) - n0;
        if (en >> 63) atomicAdd(&cntS[l], 1);
        else          atomicAdd(&cntD[l], 1);
    }
    __syncthreads();
    int tot = cntD[tx] + cntS[tx];
    tb[tx] = tot; __syncthreads();
    for (int d = 1; d < 256; d <<= 1) {
        int t2 = (tx >= d) ? tb[tx - d] : 0;
        __syncthreads();
        tb[tx] += t2;
        __syncthreads();
    }
    int obase = rs + tb[tx] - tot;           // exclusive
    if (tx < nT) {
        offsets[n0 + tx] = obase;
        dynEnd[n0 + tx]  = obase + cntD[tx];
        curD[tx] = obase;
        curS[tx] = obase + cntD[tx];
    }
    if (b == NBUCK - 1 && tx == 0) offsets[N] = E;
    __syncthreads();
    for (int i = rs + tx; i < re; i += 256) {
        unsigned long long en = csr_tmp[i];
        int l = (int)(en & 0xFFFFu) - n0;
        int pos = (en >> 63) ? atomicAdd(&curS[l], 1) : atomicAdd(&curD[l], 1);
        csr[pos] = ((unsigned)((en >> 32) & 0xFFFFu) << 16)
                 | (unsigned)((en >> 16) & 0xFFFFu);
    }
}

// init v_w[n][8] fp32, r0=r1 bf16 rows (uint4), coef2 = (1-g or 0 for Tm1, g)
__global__ void k_initv(const float* __restrict__ tm1_in, const float* __restrict__ v_init,
                        const float* __restrict__ tau_p,
                        const int* __restrict__ type_ids, const int* __restrict__ tm1_pos,
                        float* __restrict__ v_w, uint4* __restrict__ r0, uint4* __restrict__ r1,
                        float2* __restrict__ coef2, int N, int NT) {
    int n = blockIdx.x * BLK + threadIdx.x;
    if (n >= N) return;
    int k = tm1_pos[n];
    float g = DT_C / tau_p[type_ids[n]];
    coef2[n] = make_float2((k >= 0) ? 0.f : (1.f - g), g);
    float vv[NBATCH], rr[NBATCH];
    for (int b = 0; b < NBATCH; ++b) {
        float val = (k >= 0) ? tm1_in[b * NT + k] : v_init[b * N + n];
        vv[b] = val;
        rr[b] = fmaxf(val, 0.f);
    }
    float4* vp = (float4*)(v_w + (size_t)n * 8);
    vp[0] = make_float4(vv[0], vv[1], vv[2], vv[3]);
    vp[1] = make_float4(vv[4], vv[5], vv[6], vv[7]);
    uint4 rq = make_uint4(pk_bf2(rr[0], rr[1]), pk_bf2(rr[2], rr[3]),
                          pk_bf2(rr[4], rr[5]), pk_bf2(rr[6], rr[7]));
    r0[n] = rq;
    r1[n] = rq;
}

// 8-lane-group butterfly transpose-reduce (lane sub gets batch-sub sum)
__device__ __forceinline__ float butterfly8(float4 a0, float4 a1, int sub) {
    int bit0 = sub & 1, bit1 = (sub >> 1) & 1, bit2 = (sub >> 2) & 1;
    float b0 = (bit0 ? a0.y : a0.x) + __shfl_xor(bit0 ? a0.x : a0.y, 1);
    float b1 = (bit0 ? a0.w : a0.z) + __shfl_xor(bit0 ? a0.z : a0.w, 1);
    float b2 = (bit0 ? a1.y : a1.x) + __shfl_xor(bit0 ? a1.x : a1.y, 1);
    float b3 = (bit0 ? a1.w : a1.z) + __shfl_xor(bit0 ? a1.z : a1.w, 1);
    float c0 = (bit1 ? b1 : b0) + __shfl_xor(bit1 ? b0 : b1, 2);
    float c1 = (bit1 ? b3 : b2) + __shfl_xor(bit1 ? b2 : b3, 2);
    return (bit2 ? c1 : c0) + __shfl_xor(bit2 ? c0 : c1, 4);
}

// one-shot static fold: cF[n*8+sub] = (sum_static w*r_src[sub] + bias[n]) * g
__global__ void k_static(const int* __restrict__ offsets, const int* __restrict__ dynEnd,
                         const unsigned* __restrict__ csr, const uint4* __restrict__ r0,
                         const float2* __restrict__ coef2, const float* __restrict__ bias,
                         float* __restrict__ cF, int N) {
    int tid = blockIdx.x * BLK + threadIdx.x;
    int n = tid >> 3;
    int sub = threadIdx.x & 7;
    if (n >= N) return;
    float g = coef2[n].y;
    int s = dynEnd[n], e = offsets[n + 1];
    float4 a0 = make_float4(0.f, 0.f, 0.f, 0.f);
    float4 a1 = make_float4(0.f, 0.f, 0.f, 0.f);
    for (int i = s + sub; i < e; i += 8) {
        unsigned ew = csr[i];
        float w = __uint_as_float(ew & 0xFFFF0000u);
        uint4 q = r0[ew & 0xFFFFu];
        a0.x = fmaf(w, __uint_as_float(q.x << 16),          a0.x);
        a0.y = fmaf(w, __uint_as_float(q.x & 0xFFFF0000u),  a0.y);
        a0.z = fmaf(w, __uint_as_float(q.y << 16),          a0.z);
        a0.w = fmaf(w, __uint_as_float(q.y & 0xFFFF0000u),  a0.w);
        a1.x = fmaf(w, __uint_as_float(q.z << 16),          a1.x);
        a1.y = fmaf(w, __uint_as_float(q.z & 0xFFFF0000u),  a1.y);
        a1.z = fmaf(w, __uint_as_float(q.w << 16),          a1.z);
        a1.w = fmaf(w, __uint_as_float(q.w & 0xFFFF0000u),  a1.w);
    }
    float syn = butterfly8(a0, a1, sub);
    cF[(size_t)n * 8 + sub] = (syn + bias[n]) * g;
}

// step: 8-lane group per target; phases A(csr)/B(gather)/C(FMA).
// out != nullptr on the LAST step: write d_out[b][n] instead of v_w/r_next.
__global__ __launch_bounds__(BLK) void k_step(
        const int* __restrict__ offsets, const int* __restrict__ dynEnd,
        const unsigned* __restrict__ csr,
        const float2* __restrict__ coef2, const float* __restrict__ cF,
        const uv4* __restrict__ r_prev,
        float* __restrict__ v_w, unsigned short* __restrict__ r_next,
        float* __restrict__ out, int N) {
    int tid = blockIdx.x * BLK + threadIdx.x;
    int n = tid >> 3;
    int sub = threadIdx.x & 7;
    if (n >= N) return;
    float2 cf = coef2[n];
    size_t idx = (size_t)n * 8 + sub;
    if (cf.x == 0.f) {                        // Tm1 target: clamped
        if (out) out[(size_t)sub * N + n] = v_w[idx];
        return;
    }
    int s = offsets[n], e = dynEnd[n];

    float wj[PRE];
    int   sj[PRE];
    #pragma unroll
    for (int j = 0; j < PRE; ++j) {
        int i2 = s + sub + 8 * j;
        unsigned ew = (i2 < e) ? __builtin_nontemporal_load(csr + i2) : 0u;
        wj[j] = __uint_as_float(ew & 0xFFFF0000u);
        sj[j] = (int)(ew & 0xFFFFu);
    }
    uv4 q[PRE];
    #pragma unroll
    for (int j = 0; j < PRE; ++j) {
        int i2 = s + sub + 8 * j;
        q[j] = (i2 < e) ? r_prev[sj[j]] : (uv4)(0u);
    }
    float4 a0 = make_float4(0.f, 0.f, 0.f, 0.f);
    float4 a1 = make_float4(0.f, 0.f, 0.f, 0.f);
    #pragma unroll
    for (int j = 0; j < PRE; ++j) {
        float w = wj[j];
        a0.x = fmaf(w, __uint_as_float(q[j].x << 16),          a0.x);
        a0.y = fmaf(w, __uint_as_float(q[j].x & 0xFFFF0000u),  a0.y);
        a0.z = fmaf(w, __uint_as_float(q[j].y << 16),          a0.z);
        a0.w = fmaf(w, __uint_as_float(q[j].y & 0xFFFF0000u),  a0.w);
        a1.x = fmaf(w, __uint_as_float(q[j].z << 16),          a1.x);
        a1.y = fmaf(w, __uint_as_float(q[j].z & 0xFFFF0000u),  a1.y);
        a1.z = fmaf(w, __uint_as_float(q[j].w << 16),          a1.z);
        a1.w = fmaf(w, __uint_as_float(q[j].w & 0xFFFF0000u),  a1.w);
    }
    for (int i2 = s + sub + 8 * PRE; i2 < e; i2 += 8) {
        unsigned ew = __builtin_nontemporal_load(csr + i2);
        float w = __uint_as_float(ew & 0xFFFF0000u);
        uv4 qq = r_prev[ew & 0xFFFFu];
        a0.x = fmaf(w, __uint_as_float(qq.x << 16),          a0.x);
        a0.y = fmaf(w, __uint_as_float(qq.x & 0xFFFF0000u),  a0.y);
        a0.z = fmaf(w, __uint_as_float(qq.y << 16),          a0.z);
        a0.w = fmaf(w, __uint_as_float(qq.y & 0xFFFF0000u),  a0.w);
        a1.x = fmaf(w, __uint_as_float(qq.z << 16),          a1.x);
        a1.y = fmaf(w, __uint_as_float(qq.z & 0xFFFF0000u),  a1.y);
        a1.z = fmaf(w, __uint_as_float(qq.w << 16),          a1.z);
        a1.w = fmaf(w, __uint_as_float(qq.w & 0xFFFF0000u),  a1.w);
    }
    float syn = butterfly8(a0, a1, sub);
    float vo = __builtin_nontemporal_load(v_w + idx);
    float cf3 = __builtin_nontemporal_load(cF + idx);
    float vn = vo * cf.x + syn * cf.y + cf3;
    if (out) {
        out[(size_t)sub * N + n] = vn;
    } else {
        __builtin_nontemporal_store(vn, v_w + idx);
        r_next[idx] = (unsigned short)f2bf_rne(fmaxf(vn, 0.f));
    }
}

static inline size_t align16(size_t x) { return (x + 15) & ~(size_t)15; }

extern "C" void kernel_launch(void* const* d_in, const int* in_sizes, int n_in,
                              void* d_out, int out_size, void* d_ws, size_t ws_size,
                              hipStream_t stream) {
    const float* tm1_in  = (const float*)d_in[0];
    const float* v_init  = (const float*)d_in[1];
    const float* weights = (const float*)d_in[2];
    const float* bias    = (const float*)d_in[3];
    const float* tau_p   = (const float*)d_in[4];
    const float* se      = (const float*)d_in[5];
    const float* si      = (const float*)d_in[6];
    const int*   srcI    = (const int*)d_in[7];
    const int*   tgtI    = (const int*)d_in[8];
    const int*   type_ids= (const int*)d_in[9];
    const int*   tm1_idx = (const int*)d_in[10];

    const int E  = in_sizes[2];
    const int N  = in_sizes[3];
    const int NT = in_sizes[10];
    const int span = (N + NBUCK - 1) / NBUCK;   // targets per bucket (<=256)

    char* p = (char*)d_ws;
    size_t off = 0;
    auto take = [&](size_t bytes) { void* r = p + off; off += align16(bytes); return r; };
    int*      offsets = (int*)     take((size_t)(N + 1) * 4);
    int*      dynEnd  = (int*)     take((size_t)N * 4);
    int*      tm1_pos = (int*)     take((size_t)N * 4);
    int*      bcount  = (int*)     take(NBUCK * 4);
    int*      bbase   = (int*)     take((NBUCK + 1) * 4);
    int*      gCursor = (int*)     take(NBUCK * 4);
    unsigned* csr     = (unsigned*)take((size_t)E * 4);
    unsigned long long* csr_tmp = (unsigned long long*)take((size_t)E * 8);
    float2*   coef2   = (float2*)  take((size_t)N * 8);
    float*    cF      = (float*)   take((size_t)N * 8 * 4);
    float*    v_w     = (float*)   take((size_t)N * 8 * 4);
    uint4*    r0      = (uint4*)   take((size_t)N * 16);     // bf16 rows
    uint4*    r1      = (uint4*)   take((size_t)N * 16);
    (void)ws_size;

    const int gN  = (N + BLK - 1) / BLK;
    const int gNT = (NT + BLK - 1) / BLK;
    const int g8  = (N * 8 + BLK - 1) / BLK;
    const int gCH = (E + CHUNK - 1) / CHUNK;

    k_zero<<<gN, BLK, 0, stream>>>(tm1_pos, bcount, N);
    k_tm1pos<<<gNT, BLK, 0, stream>>>(tm1_idx, tm1_pos, NT);
    k_bcount<<<gCH, 256, 0, stream>>>(tgtI, bcount, E, span);
    k_bscan<<<1, NBUCK, 0, stream>>>(bcount, bbase, gCursor);
    k_bucket<<<gCH, 256, 0, stream>>>(srcI, tgtI, weights, type_ids, se, si,
                                      gCursor, csr_tmp, E, span);
    k_place<<<NBUCK, 256, 0, stream>>>(csr_tmp, bbase, csr, offsets, dynEnd,
                                       N, E, span);
    k_initv<<<gN, BLK, 0, stream>>>(tm1_in, v_init, tau_p, type_ids, tm1_pos,
                                    v_w, r0, r1, coef2, N, NT);
    k_static<<<g8, BLK, 0, stream>>>(offsets, dynEnd, csr, r0, coef2, bias, cF, N);

    uint4* rb[2] = { r0, r1 };
    for (int s = 0; s < STEPS; ++s) {
        float* outp = (s == STEPS - 1) ? (float*)d_out : nullptr;
        k_step<<<g8, BLK, 0, stream>>>(offsets, dynEnd, csr, coef2, cF,
                                       (const uv4*)rb[s & 1], v_w,
                                       (unsigned short*)rb[(s + 1) & 1],
                                       outp, N);
    }
}